// Round 1
// baseline (111.417 us; speedup 1.0000x reference)
//
#include <hip/hip_runtime.h>

// Problem constants (B,S,D,R) = (8,512,768,128)
#define NB 8
#define NS 512
#define ND 768
#define NR 128
#define NM (NB * NS)                       // 4096 rows total
#define DIST_ELEMS ((size_t)NB * NS * NS)  // 2097152

// ---------------------------------------------------------------------------
// Kernel 1: projection GEMM.
//   C = emb(4096x768) @ concat(proj_dist, proj_depth)^T(768x256)
// grid (4, 64), block 256. blockIdx.x: 0,1 -> dist halves (write P to ws),
//                                      2,3 -> depth halves (square-reduce -> atomicAdd depths)
// LDS tiles store float4 granules XOR-swizzled by ((row>>2)&7) so that the
// stride-4-row b128 read pattern (bf[j]: rows tx*4+j) is bank-conflict-free.
// ---------------------------------------------------------------------------
constexpr int BM = 64;
constexpr int BN = 64;
constexpr int KT = 32;

__global__ __launch_bounds__(256) void proj_kernel(
    const float* __restrict__ emb,
    const float* __restrict__ projD,
    const float* __restrict__ projP,
    float* __restrict__ P,
    float* __restrict__ depths)
{
  __shared__ float sA[BM][KT];
  __shared__ float sB[BN][KT];

  const int tid = threadIdx.x;
  const int ct  = blockIdx.x;
  const int m0  = blockIdx.y * BM;
  const bool isDepth = (ct >= 2);
  const int n0  = (ct & 1) * BN;
  const float* proj = isDepth ? projP : projD;

  // staging: 64 rows x 8 granules(16B) per tile = 512 float4; 2 per thread
  const int srow = tid >> 2;        // 0..63
  const int sg0  = tid & 3;         // granules sg0 and sg0+4
  const int ssw  = (srow >> 2) & 7; // swizzle for this staged row
  const float* aRow = emb  + (size_t)(m0 + srow) * ND;
  const float* bRow = proj + (size_t)(n0 + srow) * ND;

  // prefetch tile 0 into registers
  float4 a0 = *(const float4*)(aRow + sg0 * 4);
  float4 a1 = *(const float4*)(aRow + (sg0 + 4) * 4);
  float4 b0 = *(const float4*)(bRow + sg0 * 4);
  float4 b1 = *(const float4*)(bRow + (sg0 + 4) * 4);

  const int ty = tid >> 4;   // 0..15 row group (4 rows)
  const int tx = tid & 15;   // 0..15 col group (4 cols)

  float acc[4][4] = {};

  for (int kt = 0; kt < ND; kt += KT) {
    *(float4*)(&sA[srow][((sg0    ) ^ ssw) * 4]) = a0;
    *(float4*)(&sA[srow][((sg0 + 4) ^ ssw) * 4]) = a1;
    *(float4*)(&sB[srow][((sg0    ) ^ ssw) * 4]) = b0;
    *(float4*)(&sB[srow][((sg0 + 4) ^ ssw) * 4]) = b1;
    __syncthreads();
    if (kt + KT < ND) {  // register prefetch of next K-tile (hides global latency)
      a0 = *(const float4*)(aRow + kt + KT + sg0 * 4);
      a1 = *(const float4*)(aRow + kt + KT + (sg0 + 4) * 4);
      b0 = *(const float4*)(bRow + kt + KT + sg0 * 4);
      b1 = *(const float4*)(bRow + kt + KT + (sg0 + 4) * 4);
    }
    #pragma unroll
    for (int g = 0; g < KT / 4; ++g) {
      float4 af[4], bf[4];
      #pragma unroll
      for (int i = 0; i < 4; ++i) {
        const int row = ty * 4 + i;
        af[i] = *(const float4*)(&sA[row][(g ^ ((row >> 2) & 7)) * 4]);
      }
      #pragma unroll
      for (int j = 0; j < 4; ++j) {
        const int row = tx * 4 + j;
        bf[j] = *(const float4*)(&sB[row][(g ^ ((row >> 2) & 7)) * 4]);
      }
      #pragma unroll
      for (int i = 0; i < 4; ++i)
        #pragma unroll
        for (int j = 0; j < 4; ++j) {
          acc[i][j] += af[i].x * bf[j].x;
          acc[i][j] += af[i].y * bf[j].y;
          acc[i][j] += af[i].z * bf[j].z;
          acc[i][j] += af[i].w * bf[j].w;
        }
    }
    __syncthreads();
  }

  if (!isDepth) {
    #pragma unroll
    for (int i = 0; i < 4; ++i) {
      float4 v = make_float4(acc[i][0], acc[i][1], acc[i][2], acc[i][3]);
      *(float4*)(P + (size_t)(m0 + ty * 4 + i) * NR + n0 + tx * 4) = v;
    }
  } else {
    // depths[m] += sum over this block's 64 cols of p^2 ; reduce across the
    // 16 tx lanes (consecutive lanes within the wave), then one atomic/row.
    #pragma unroll
    for (int i = 0; i < 4; ++i) {
      float s = acc[i][0] * acc[i][0] + acc[i][1] * acc[i][1]
              + acc[i][2] * acc[i][2] + acc[i][3] * acc[i][3];
      s += __shfl_xor(s, 1);
      s += __shfl_xor(s, 2);
      s += __shfl_xor(s, 4);
      s += __shfl_xor(s, 8);
      if (tx == 0) atomicAdd(&depths[m0 + ty * 4 + i], s);
    }
  }
}

// ---------------------------------------------------------------------------
// Kernel 2: distances[b,i,j] = nI[i] + nJ[j] - 2 * (P_b P_b^T)[i,j]
// grid (8, 8, 8) = (j-tile, i-tile, batch), block 256, 64x64 tile, K chunked
// at 64 so static LDS stays under 64 KB. Same XOR-swizzled LDS layout.
// ---------------------------------------------------------------------------
constexpr int BT = 64;
constexpr int KC = 64;

__global__ __launch_bounds__(256) void dist_kernel(
    const float* __restrict__ P,
    float* __restrict__ out)
{
  __shared__ float sPi[BT][KC];
  __shared__ float sPj[BT][KC];
  __shared__ float nI[BT], nJ[BT];

  const int tid = threadIdx.x;
  const int b  = blockIdx.z;
  const int i0 = blockIdx.y * BT;
  const int j0 = blockIdx.x * BT;
  const float* Pb = P + (size_t)b * NS * NR;

  if (tid < BT) nI[tid] = 0.f;
  else if (tid < 2 * BT) nJ[tid - BT] = 0.f;

  const int ty = tid >> 4, tx = tid & 15;
  float acc[4][4] = {};

  for (int kc = 0; kc < NR; kc += KC) {
    __syncthreads();  // nI init / previous chunk's reads complete before restage
    #pragma unroll
    for (int t4 = 0; t4 < 4; ++t4) {
      const int t   = tid + t4 * 256;  // 0..1023
      const int row = t >> 4;          // 0..63
      const int g   = t & 15;          // 0..15
      const int sw  = (row >> 2) & 7;
      float4 vi = *(const float4*)(Pb + (size_t)(i0 + row) * NR + kc + g * 4);
      float4 vj = *(const float4*)(Pb + (size_t)(j0 + row) * NR + kc + g * 4);
      *(float4*)(&sPi[row][((g ^ sw) & 15) * 4]) = vi;
      *(float4*)(&sPj[row][((g ^ sw) & 15) * 4]) = vj;
    }
    __syncthreads();

    // partial norms for this K-chunk (threads 0..127; read-only vs main loop)
    if (tid < 2 * BT) {
      const int row = tid & (BT - 1);
      const float* sp = (tid < BT) ? &sPi[0][0] : &sPj[0][0];
      const int sw = (row >> 2) & 7;
      float s = 0.f;
      #pragma unroll
      for (int g = 0; g < KC / 4; ++g) {
        const float4 v = *(const float4*)(sp + row * KC + ((g ^ sw) & 15) * 4);
        s += v.x * v.x + v.y * v.y + v.z * v.z + v.w * v.w;
      }
      if (tid < BT) nI[row] += s; else nJ[row] += s;
    }

    #pragma unroll
    for (int g = 0; g < KC / 4; ++g) {
      float4 af[4], bf[4];
      #pragma unroll
      for (int i = 0; i < 4; ++i) {
        const int row = ty * 4 + i;
        af[i] = *(const float4*)(&sPi[row][((g ^ ((row >> 2) & 7)) & 15) * 4]);
      }
      #pragma unroll
      for (int j = 0; j < 4; ++j) {
        const int row = tx * 4 + j;
        bf[j] = *(const float4*)(&sPj[row][((g ^ ((row >> 2) & 7)) & 15) * 4]);
      }
      #pragma unroll
      for (int i = 0; i < 4; ++i)
        #pragma unroll
        for (int j = 0; j < 4; ++j) {
          acc[i][j] += af[i].x * bf[j].x;
          acc[i][j] += af[i].y * bf[j].y;
          acc[i][j] += af[i].z * bf[j].z;
          acc[i][j] += af[i].w * bf[j].w;
        }
    }
  }
  __syncthreads();

  float* ob = out + ((size_t)b * NS + i0) * NS + j0;
  #pragma unroll
  for (int i = 0; i < 4; ++i) {
    const int row = ty * 4 + i;
    const float ni = nI[row];
    float4 v;
    v.x = ni + nJ[tx * 4 + 0] - 2.f * acc[i][0];
    v.y = ni + nJ[tx * 4 + 1] - 2.f * acc[i][1];
    v.z = ni + nJ[tx * 4 + 2] - 2.f * acc[i][2];
    v.w = ni + nJ[tx * 4 + 3] - 2.f * acc[i][3];
    *(float4*)(ob + (size_t)row * NS + tx * 4) = v;
  }
}

// ---------------------------------------------------------------------------
extern "C" void kernel_launch(void* const* d_in, const int* in_sizes, int n_in,
                              void* d_out, int out_size, void* d_ws, size_t ws_size,
                              hipStream_t stream) {
  const float* emb   = (const float*)d_in[0];
  const float* projD = (const float*)d_in[1];
  const float* projP = (const float*)d_in[2];
  float* out = (float*)d_out;
  float* P = (float*)d_ws;                       // 4096x128 fp32 = 2 MB scratch
  float* depths = out + DIST_ELEMS;              // second output, [4096]

  // depths accumulated via atomics across two col-half blocks -> pre-zero
  hipMemsetAsync(depths, 0, NM * sizeof(float), stream);

  dim3 g1(4, NM / BM);           // 4 col-tiles (2 dist + 2 depth) x 64 row-tiles
  proj_kernel<<<g1, 256, 0, stream>>>(emb, projD, projP, P, depths);

  dim3 g2(NS / BT, NS / BT, NB); // 8 x 8 x 8
  dist_kernel<<<g2, 256, 0, stream>>>(P, out);
}

// Round 3
// 88.676 us; speedup vs baseline: 1.2564x; 1.2564x over previous
//
#include <hip/hip_runtime.h>

// Problem constants (B,S,D,R) = (8,512,768,128)
#define NB 8
#define NS 512
#define ND 768
#define NR 128
#define NM (NB * NS)                       // 4096 rows total
#define DIST_ELEMS ((size_t)NB * NS * NS)  // 2097152

typedef short bf16x8 __attribute__((ext_vector_type(8)));  // 8 bf16 (4 VGPRs)
typedef float f32x4  __attribute__((ext_vector_type(4)));  // MFMA C/D frag

__device__ __forceinline__ unsigned short f2bf(float f) {  // RNE fp32 -> bf16 bits
  unsigned int u = __float_as_uint(f);
  return (unsigned short)((u + 0x7FFFu + ((u >> 16) & 1u)) >> 16);
}
__device__ __forceinline__ float bf2f(unsigned short h) {
  return __uint_as_float(((unsigned int)h) << 16);
}

// ---------------------------------------------------------------------------
// Kernel 1: C = emb(4096x768) @ concat(projD,projP)^T(768x256), bf16 MFMA.
// grid (4, 64): x<2 -> dist halves (write bf16 P + norms), x>=2 -> depth halves
// (depths). 64x64 tile, 4 waves; wave w computes cols [16w,16w+16), 4 M-frags.
// LDS rows = 32 bf16 (64 B): frag b128 reads are dense/conflict-free.
// ---------------------------------------------------------------------------
constexpr int KT = 32;

__global__ __launch_bounds__(256) void proj_kernel(
    const float* __restrict__ emb,
    const float* __restrict__ projD,
    const float* __restrict__ projP,
    unsigned short* __restrict__ P,       // bf16 bits, 4096x128
    float* __restrict__ normsD,           // [4096] pre-zeroed
    float* __restrict__ depths)           // [4096] pre-zeroed (output)
{
  __shared__ unsigned short sA[64][KT];
  __shared__ unsigned short sB[64][KT];

  const int tid = threadIdx.x;
  const int ct  = blockIdx.x;
  const bool isDepth = (ct >= 2);
  const int n0  = (ct & 1) * 64;          // col offset within the 128-proj
  const int m0  = blockIdx.y * 64;
  const float* proj = (isDepth ? projP : projD) + (size_t)n0 * ND;

  // staging: thread t handles row t>>2, k-octet t&3 (8 floats -> 8 bf16 = 16 B)
  const int srow = tid >> 2;
  const int skq  = tid & 3;
  const float* aRow = emb  + (size_t)(m0 + srow) * ND + skq * 8;
  const float* bRow = proj + (size_t)srow * ND + skq * 8;

  float4 a0 = *(const float4*)(aRow);
  float4 a1 = *(const float4*)(aRow + 4);
  float4 b0 = *(const float4*)(bRow);
  float4 b1 = *(const float4*)(bRow + 4);

  const int lane = tid & 63;
  const int w    = tid >> 6;
  const int ln   = lane & 15;
  const int q    = lane >> 4;

  f32x4 acc[4] = {};

  for (int kt = 0; kt < ND; kt += KT) {
    bf16x8 pa, pb;
    pa[0] = f2bf(a0.x); pa[1] = f2bf(a0.y); pa[2] = f2bf(a0.z); pa[3] = f2bf(a0.w);
    pa[4] = f2bf(a1.x); pa[5] = f2bf(a1.y); pa[6] = f2bf(a1.z); pa[7] = f2bf(a1.w);
    pb[0] = f2bf(b0.x); pb[1] = f2bf(b0.y); pb[2] = f2bf(b0.z); pb[3] = f2bf(b0.w);
    pb[4] = f2bf(b1.x); pb[5] = f2bf(b1.y); pb[6] = f2bf(b1.z); pb[7] = f2bf(b1.w);
    *(bf16x8*)(&sA[srow][skq * 8]) = pa;
    *(bf16x8*)(&sB[srow][skq * 8]) = pb;
    __syncthreads();
    if (kt + KT < ND) {  // register prefetch of next K-tile
      a0 = *(const float4*)(aRow + kt + KT);
      a1 = *(const float4*)(aRow + kt + KT + 4);
      b0 = *(const float4*)(bRow + kt + KT);
      b1 = *(const float4*)(bRow + kt + KT + 4);
    }
    bf16x8 bq = *(const bf16x8*)(&sB[16 * w + ln][q * 8]);
    #pragma unroll
    for (int i = 0; i < 4; ++i) {
      bf16x8 aq = *(const bf16x8*)(&sA[16 * i + ln][q * 8]);
      acc[i] = __builtin_amdgcn_mfma_f32_16x16x32_bf16(aq, bq, acc[i], 0, 0, 0);
    }
    __syncthreads();
  }

  // Epilogue. C/D layout: col = lane&15 (-> proj col n0+16w+ln),
  // row = q*4 + reg (+16i). Round to bf16 FIRST so norms match the P that
  // kernel 2's MFMA consumes (keeps the distance diagonal ~0).
  const int nG = n0 + 16 * w + ln;
  float* target = isDepth ? depths : normsD;
  #pragma unroll
  for (int i = 0; i < 4; ++i) {
    float vs[4];
    #pragma unroll
    for (int r = 0; r < 4; ++r) {
      unsigned short hb = f2bf(acc[i][r]);
      if (!isDepth)
        P[(size_t)(m0 + 16 * i + 4 * q + r) * NR + nG] = hb;
      float v = bf2f(hb);
      vs[r] = v * v;
    }
    #pragma unroll
    for (int r = 0; r < 4; ++r) {
      float s = vs[r];
      s += __shfl_xor(s, 1);
      s += __shfl_xor(s, 2);
      s += __shfl_xor(s, 4);
      s += __shfl_xor(s, 8);
      if (ln == 0) atomicAdd(&target[m0 + 16 * i + 4 * q + r], s);
    }
  }
}

// ---------------------------------------------------------------------------
// Kernel 2: out[b,i,j] = n[i] + n[j] - 2 * (Pb Pb^T)[i,j], bf16 MFMA, K=128
// staged once. grid (8,8,8), 64x64 tile, 4 waves. LDS rows padded to 136 bf16
// (272 B = 68 dwords ≡ 4 banks/row shift -> 2-way conflict = free).
// normsD is indexed by GLOBAL row m = b*NS + s  (round-2 bug: missed b*NS).
// ---------------------------------------------------------------------------
__global__ __launch_bounds__(256) void dist_kernel(
    const unsigned short* __restrict__ P,
    const float* __restrict__ normsD,
    float* __restrict__ out)
{
  __shared__ unsigned short sPi[64][136];
  __shared__ unsigned short sPj[64][136];
  __shared__ float nIs[64], nJs[64];

  const int tid = threadIdx.x;
  const int b  = blockIdx.z;
  const int i0 = blockIdx.y * 64;
  const int j0 = blockIdx.x * 64;
  const unsigned short* Pb = P + (size_t)b * NS * NR;
  const float* normsB = normsD + (size_t)b * NS;   // <-- batch offset (the fix)

  // stage 64x128 bf16 tiles; 16 lanes cover one 256 B row -> coalesced
  const int grow = tid >> 4;  // 0..15
  const int gg   = tid & 15;  // 16 B granule within row
  #pragma unroll
  for (int jj = 0; jj < 4; ++jj) {
    const int row = grow + jj * 16;
    float4 vi = *(const float4*)(Pb + (size_t)(i0 + row) * NR + gg * 8);
    float4 vj = *(const float4*)(Pb + (size_t)(j0 + row) * NR + gg * 8);
    *(float4*)(&sPi[row][gg * 8]) = vi;
    *(float4*)(&sPj[row][gg * 8]) = vj;
  }
  if (tid < 64)       nIs[tid]      = normsB[i0 + tid];
  else if (tid < 128) nJs[tid - 64] = normsB[j0 + tid - 64];
  __syncthreads();

  const int lane = tid & 63;
  const int w    = tid >> 6;
  const int ln   = lane & 15;
  const int q    = lane >> 4;

  f32x4 acc[4] = {};
  #pragma unroll
  for (int ks = 0; ks < 4; ++ks) {
    bf16x8 bq = *(const bf16x8*)(&sPj[16 * w + ln][ks * 32 + q * 8]);
    #pragma unroll
    for (int i = 0; i < 4; ++i) {
      bf16x8 aq = *(const bf16x8*)(&sPi[16 * i + ln][ks * 32 + q * 8]);
      acc[i] = __builtin_amdgcn_mfma_f32_16x16x32_bf16(aq, bq, acc[i], 0, 0, 0);
    }
  }

  const int col = j0 + 16 * w + ln;
  const float nj = nJs[16 * w + ln];
  float* ob = out + (size_t)b * NS * NS;
  #pragma unroll
  for (int i = 0; i < 4; ++i) {
    #pragma unroll
    for (int r = 0; r < 4; ++r) {
      const int rloc = 16 * i + 4 * q + r;
      ob[(size_t)(i0 + rloc) * NS + col] = nIs[rloc] + nj - 2.0f * acc[i][r];
    }
  }
}

// ---------------------------------------------------------------------------
extern "C" void kernel_launch(void* const* d_in, const int* in_sizes, int n_in,
                              void* d_out, int out_size, void* d_ws, size_t ws_size,
                              hipStream_t stream) {
  const float* emb   = (const float*)d_in[0];
  const float* projD = (const float*)d_in[1];
  const float* projP = (const float*)d_in[2];
  float* out = (float*)d_out;

  unsigned short* P = (unsigned short*)d_ws;                       // 1 MB bf16
  float* normsD = (float*)((char*)d_ws + (size_t)NM * NR * 2);     // 16 KB
  float* depths = out + DIST_ELEMS;                                // output [4096]

  hipMemsetAsync(normsD, 0, NM * sizeof(float), stream);
  hipMemsetAsync(depths, 0, NM * sizeof(float), stream);

  proj_kernel<<<dim3(4, NM / 64), 256, 0, stream>>>(emb, projD, projP, P, normsD, depths);
  dist_kernel<<<dim3(NS / 64, NS / 64, NB), 256, 0, stream>>>(P, normsD, out);
}

// Round 4
// 85.620 us; speedup vs baseline: 1.3013x; 1.0357x over previous
//
#include <hip/hip_runtime.h>

// Problem constants (B,S,D,R) = (8,512,768,128)
#define NB 8
#define NS 512
#define ND 768
#define NR 128
#define NM (NB * NS)                       // 4096 rows total
#define DIST_ELEMS ((size_t)NB * NS * NS)  // 2097152

typedef short bf16x8 __attribute__((ext_vector_type(8)));  // 8 bf16 (4 VGPRs)
typedef float f32x4  __attribute__((ext_vector_type(4)));  // MFMA C/D frag

__device__ __forceinline__ unsigned short f2bf(float f) {  // RNE fp32 -> bf16 bits
  unsigned int u = __float_as_uint(f);
  return (unsigned short)((u + 0x7FFFu + ((u >> 16) & 1u)) >> 16);
}
__device__ __forceinline__ float bf2f(unsigned short h) {
  return __uint_as_float(((unsigned int)h) << 16);
}
__device__ __forceinline__ bf16x8 pack8(float4 lo, float4 hi) {
  bf16x8 p;
  p[0] = (short)f2bf(lo.x); p[1] = (short)f2bf(lo.y);
  p[2] = (short)f2bf(lo.z); p[3] = (short)f2bf(lo.w);
  p[4] = (short)f2bf(hi.x); p[5] = (short)f2bf(hi.y);
  p[6] = (short)f2bf(hi.z); p[7] = (short)f2bf(hi.w);
  return p;
}

// ---------------------------------------------------------------------------
// Kernel 1: proj GEMM, bf16 MFMA, M-tile 32 for occupancy.
// grid (3, 128), block 256 (4 waves):
//   ct=0: P cols 0-63 (projD)   ct=1: P cols 64-127 (projD)
//   ct=2: depths = rowsum(p^2) over all 128 projP cols -> direct store
// LDS rows = 32 bf16 (64 B): frag b128 reads are dense/conflict-free.
// ---------------------------------------------------------------------------
constexpr int KT = 32;

__global__ __launch_bounds__(256) void proj_kernel(
    const float* __restrict__ emb,
    const float* __restrict__ projD,
    const float* __restrict__ projP,
    unsigned short* __restrict__ P,       // bf16 bits, 4096x128
    float* __restrict__ depths)           // [4096] output, direct store
{
  __shared__ unsigned short sA[32][KT];   // 2 KB
  __shared__ unsigned short sB[128][KT];  // 8 KB (dist blocks use rows 0-63)
  __shared__ float sRed[4][32];           // depth cross-wave reduce

  const int tid = threadIdx.x;
  const int ct  = blockIdx.x;
  const bool isDepth = (ct == 2);
  const int m0  = blockIdx.y * 32;
  const float* proj = isDepth ? projP : (projD + (size_t)(ct * 64) * ND);

  // A staging: 32 rows x 4 octets = 128 octets -> threads 0..127 (waves 0-1)
  const int arow = tid >> 2;              // valid when tid<128: 0..31
  const int aoct = tid & 3;
  const float* aPtr = emb + (size_t)(m0 + (arow & 31)) * ND + aoct * 8;
  // B staging: octet o = tid (+256 for depth's upper 64 rows)
  const int brow0 = tid >> 2;             // 0..63
  const int boct  = tid & 3;
  const float* bPtr0 = proj + (size_t)brow0 * ND + boct * 8;
  const float* bPtr1 = proj + (size_t)(brow0 + 64) * ND + boct * 8;

  float4 a0, a1, b00, b01, b10, b11;
  if (tid < 128) { a0 = *(const float4*)aPtr; a1 = *(const float4*)(aPtr + 4); }
  b00 = *(const float4*)bPtr0; b01 = *(const float4*)(bPtr0 + 4);
  if (isDepth) { b10 = *(const float4*)bPtr1; b11 = *(const float4*)(bPtr1 + 4); }

  const int lane = tid & 63;
  const int w    = tid >> 6;
  const int ln   = lane & 15;
  const int q    = lane >> 4;

  f32x4 acc[2][2] = {};   // [col-frag][row-frag]; dist uses acc[0][*] only

  for (int kt = 0; kt < ND; kt += KT) {
    if (tid < 128) *(bf16x8*)(&sA[arow & 31][aoct * 8]) = pack8(a0, a1);
    *(bf16x8*)(&sB[brow0][boct * 8]) = pack8(b00, b01);
    if (isDepth) *(bf16x8*)(&sB[brow0 + 64][boct * 8]) = pack8(b10, b11);
    __syncthreads();
    if (kt + KT < ND) {  // register prefetch of next K-tile
      if (tid < 128) {
        a0 = *(const float4*)(aPtr + kt + KT);
        a1 = *(const float4*)(aPtr + kt + KT + 4);
      }
      b00 = *(const float4*)(bPtr0 + kt + KT);
      b01 = *(const float4*)(bPtr0 + kt + KT + 4);
      if (isDepth) {
        b10 = *(const float4*)(bPtr1 + kt + KT);
        b11 = *(const float4*)(bPtr1 + kt + KT + 4);
      }
    }
    bf16x8 bq0 = *(const bf16x8*)(&sB[16 * w + ln][q * 8]);
    if (!isDepth) {
      #pragma unroll
      for (int i = 0; i < 2; ++i) {
        bf16x8 aq = *(const bf16x8*)(&sA[16 * i + ln][q * 8]);
        acc[0][i] = __builtin_amdgcn_mfma_f32_16x16x32_bf16(aq, bq0, acc[0][i], 0, 0, 0);
      }
    } else {
      bf16x8 bq1 = *(const bf16x8*)(&sB[64 + 16 * w + ln][q * 8]);
      #pragma unroll
      for (int i = 0; i < 2; ++i) {
        bf16x8 aq = *(const bf16x8*)(&sA[16 * i + ln][q * 8]);
        acc[0][i] = __builtin_amdgcn_mfma_f32_16x16x32_bf16(aq, bq0, acc[0][i], 0, 0, 0);
        acc[1][i] = __builtin_amdgcn_mfma_f32_16x16x32_bf16(aq, bq1, acc[1][i], 0, 0, 0);
      }
    }
    __syncthreads();
  }

  // Epilogue. C/D layout: col = lane&15, row = 16i + 4q + reg.
  if (!isDepth) {
    const int nG = ct * 64 + 16 * w + ln;
    #pragma unroll
    for (int i = 0; i < 2; ++i)
      #pragma unroll
      for (int r = 0; r < 4; ++r)
        P[(size_t)(m0 + 16 * i + 4 * q + r) * NR + nG] = f2bf(acc[0][i][r]);
  } else {
    // lane holds cols {16w+ln, 64+16w+ln}; reduce over 16 ln-lanes -> 32-col
    // partial per wave, then cross-wave via LDS, direct store (no atomics).
    #pragma unroll
    for (int i = 0; i < 2; ++i)
      #pragma unroll
      for (int r = 0; r < 4; ++r) {
        float s = acc[0][i][r] * acc[0][i][r] + acc[1][i][r] * acc[1][i][r];
        s += __shfl_xor(s, 1);
        s += __shfl_xor(s, 2);
        s += __shfl_xor(s, 4);
        s += __shfl_xor(s, 8);
        if (ln == 0) sRed[w][16 * i + 4 * q + r] = s;
      }
    __syncthreads();
    if (tid < 32)
      depths[m0 + tid] = sRed[0][tid] + sRed[1][tid] + sRed[2][tid] + sRed[3][tid];
  }
}

// ---------------------------------------------------------------------------
// Kernel 2: out[b,i,j] = n[i] + n[j] - 2 * (Pb Pb^T)[i,j], bf16 MFMA, K=128.
// grid (8,8,8), 64x64 tile, 4 waves. Row stride 136 bf16 (272 B -> 2-way
// bank alias = free). Norms computed in-kernel from the staged LDS tiles.
// ---------------------------------------------------------------------------
__global__ __launch_bounds__(256) void dist_kernel(
    const unsigned short* __restrict__ P,
    float* __restrict__ out)
{
  __shared__ unsigned short sPi[64][136];
  __shared__ unsigned short sPj[64][136];
  __shared__ float nIs[64], nJs[64];

  const int tid = threadIdx.x;
  const int b  = blockIdx.z;
  const int i0 = blockIdx.y * 64;
  const int j0 = blockIdx.x * 64;
  const unsigned short* Pb = P + (size_t)b * NS * NR;

  // stage 64x128 bf16 tiles; 16 lanes cover one 256 B row -> coalesced
  const int grow = tid >> 4;  // 0..15
  const int gg   = tid & 15;  // 16 B granule within row
  #pragma unroll
  for (int jj = 0; jj < 4; ++jj) {
    const int row = grow + jj * 16;
    float4 vi = *(const float4*)(Pb + (size_t)(i0 + row) * NR + gg * 8);
    float4 vj = *(const float4*)(Pb + (size_t)(j0 + row) * NR + gg * 8);
    *(float4*)(&sPi[row][gg * 8]) = vi;
    *(float4*)(&sPj[row][gg * 8]) = vj;
  }
  __syncthreads();

  // norms from LDS: thread pair (row, half) -> 64 elems each, shfl-combine
  {
    const int half = tid & 1;
    const int row  = (tid >> 1) & 63;
    const unsigned short* sp = (tid < 128) ? &sPi[row][half * 64]
                                           : &sPj[row][half * 64];
    float s = 0.f;
    #pragma unroll
    for (int g = 0; g < 8; ++g) {
      bf16x8 v = *(const bf16x8*)(sp + g * 8);
      #pragma unroll
      for (int e = 0; e < 8; ++e) {
        float f = bf2f((unsigned short)v[e]);
        s += f * f;
      }
    }
    s += __shfl_xor(s, 1);
    if (half == 0) { if (tid < 128) nIs[row] = s; else nJs[row] = s; }
  }
  __syncthreads();

  const int lane = tid & 63;
  const int w    = tid >> 6;
  const int ln   = lane & 15;
  const int q    = lane >> 4;

  f32x4 acc[4] = {};
  #pragma unroll
  for (int ks = 0; ks < 4; ++ks) {
    bf16x8 bq = *(const bf16x8*)(&sPj[16 * w + ln][ks * 32 + q * 8]);
    #pragma unroll
    for (int i = 0; i < 4; ++i) {
      bf16x8 aq = *(const bf16x8*)(&sPi[16 * i + ln][ks * 32 + q * 8]);
      acc[i] = __builtin_amdgcn_mfma_f32_16x16x32_bf16(aq, bq, acc[i], 0, 0, 0);
    }
  }

  const int col = j0 + 16 * w + ln;
  const float nj = nJs[16 * w + ln];
  float* ob = out + (size_t)b * NS * NS;
  #pragma unroll
  for (int i = 0; i < 4; ++i) {
    #pragma unroll
    for (int r = 0; r < 4; ++r) {
      const int rloc = 16 * i + 4 * q + r;
      ob[(size_t)(i0 + rloc) * NS + col] = nIs[rloc] + nj - 2.0f * acc[i][r];
    }
  }
}

// ---------------------------------------------------------------------------
extern "C" void kernel_launch(void* const* d_in, const int* in_sizes, int n_in,
                              void* d_out, int out_size, void* d_ws, size_t ws_size,
                              hipStream_t stream) {
  const float* emb   = (const float*)d_in[0];
  const float* projD = (const float*)d_in[1];
  const float* projP = (const float*)d_in[2];
  float* out = (float*)d_out;

  unsigned short* P = (unsigned short*)d_ws;     // bf16, 4096x128 = 1 MB
  float* depths = out + DIST_ELEMS;              // output [4096]

  proj_kernel<<<dim3(3, NM / 32), 256, 0, stream>>>(emb, projD, projP, P, depths);
  dist_kernel<<<dim3(NS / 64, NS / 64, NB), 256, 0, stream>>>(P, out);
}

// Round 5
// 84.347 us; speedup vs baseline: 1.3209x; 1.0151x over previous
//
#include <hip/hip_runtime.h>

// Problem constants (B,S,D,R) = (8,512,768,128)
#define NB 8
#define NS 512
#define ND 768
#define NR 128
#define NM (NB * NS)                       // 4096 rows total
#define DIST_ELEMS ((size_t)NB * NS * NS)  // 2097152

typedef short bf16x8 __attribute__((ext_vector_type(8)));  // 8 bf16 (4 VGPRs)
typedef float f32x4  __attribute__((ext_vector_type(4)));  // MFMA C/D frag

// round-half-up fp32->bf16: 2 VALU ops (vs 4 for RNE); ±1ulp of RNE, and the
// SAME rounding feeds P, the norms, and the Gram MFMA, so d(i,i) stays ~0.
__device__ __forceinline__ unsigned short f2bf(float f) {
  return (unsigned short)((__float_as_uint(f) + 0x8000u) >> 16);
}
__device__ __forceinline__ float bf2f(unsigned short h) {
  return __uint_as_float(((unsigned int)h) << 16);
}
__device__ __forceinline__ bf16x8 pack8(float4 lo, float4 hi) {
  bf16x8 p;
  p[0] = (short)f2bf(lo.x); p[1] = (short)f2bf(lo.y);
  p[2] = (short)f2bf(lo.z); p[3] = (short)f2bf(lo.w);
  p[4] = (short)f2bf(hi.x); p[5] = (short)f2bf(hi.y);
  p[6] = (short)f2bf(hi.z); p[7] = (short)f2bf(hi.w);
  return p;
}

// ---------------------------------------------------------------------------
// Kernel 1: proj GEMM, bf16 MFMA, M-tile 32, KT=64 (12 barrier iterations).
// grid (3, 128), block 256 (4 waves):
//   ct=0: P cols 0-63  (projD)  -> writes P + norm partial nP0
//   ct=1: P cols 64-127(projD)  -> writes P + norm partial nP1
//   ct=2: depths = rowsum((emb@projP)^2), all 128 cols, direct store
// LDS row stride 72 bf16 (36 dw === 4 mod 32): frag reads and staging writes
// sit at the b128 bank floor (stride 64 would be 2x the floor).
// ---------------------------------------------------------------------------
constexpr int KT  = 64;
constexpr int SAS = 72;

__global__ __launch_bounds__(256) void proj_kernel(
    const float* __restrict__ emb,
    const float* __restrict__ projD,
    const float* __restrict__ projP,
    unsigned short* __restrict__ P,       // bf16 bits, 4096x128
    float* __restrict__ nP0,              // [4096] norm partial, cols 0-63
    float* __restrict__ nP1,              // [4096] norm partial, cols 64-127
    float* __restrict__ depths)           // [4096] output, direct store
{
  __shared__ unsigned short sA[32][SAS];   // 4.6 KB
  __shared__ unsigned short sB[128][SAS];  // 18.4 KB (dist ct uses rows 0-63)
  __shared__ float sRed[4][32];

  const int tid = threadIdx.x;
  const int ct  = blockIdx.x;
  const bool isDepth = (ct == 2);
  const int m0  = blockIdx.y * 32;
  const float* proj = isDepth ? projP : (projD + (size_t)(ct * 64) * ND);

  // A staging: 32 rows x 8 octets(8 fp32) -> thread t: row t>>3, oct t&7
  const int ar = tid >> 3, ao = tid & 7;
  const float* aPtr = emb + (size_t)(m0 + ar) * ND + ao * 8;
  // B staging: thread t: row t>>2 (0..63), octets t&3 and (t&3)+4;
  // depth ct additionally rows +64.
  const int br = tid >> 2, bo = tid & 3;
  const float* bPtr0 = proj + (size_t)br * ND + bo * 8;
  const float* bPtr1 = proj + (size_t)(br + 64) * ND + bo * 8;  // depth only

  float4 a0, a1, c00, c01, c02, c03, d00, d01, d02, d03;
  a0  = *(const float4*)(aPtr);       a1  = *(const float4*)(aPtr + 4);
  c00 = *(const float4*)(bPtr0);      c01 = *(const float4*)(bPtr0 + 4);
  c02 = *(const float4*)(bPtr0 + 32); c03 = *(const float4*)(bPtr0 + 36);
  if (isDepth) {
    d00 = *(const float4*)(bPtr1);      d01 = *(const float4*)(bPtr1 + 4);
    d02 = *(const float4*)(bPtr1 + 32); d03 = *(const float4*)(bPtr1 + 36);
  }

  const int lane = tid & 63;
  const int w    = tid >> 6;
  const int ln   = lane & 15;
  const int q    = lane >> 4;

  f32x4 acc[2][2] = {};   // [col-half][row-frag]; dist uses acc[0][*]

  for (int kt = 0; kt < ND; kt += KT) {
    *(bf16x8*)(&sA[ar][ao * 8])       = pack8(a0, a1);
    *(bf16x8*)(&sB[br][bo * 8])       = pack8(c00, c01);
    *(bf16x8*)(&sB[br][(bo + 4) * 8]) = pack8(c02, c03);
    if (isDepth) {
      *(bf16x8*)(&sB[br + 64][bo * 8])       = pack8(d00, d01);
      *(bf16x8*)(&sB[br + 64][(bo + 4) * 8]) = pack8(d02, d03);
    }
    __syncthreads();
    if (kt + KT < ND) {  // register prefetch of next K-tile
      const int o = kt + KT;
      a0  = *(const float4*)(aPtr + o);       a1  = *(const float4*)(aPtr + o + 4);
      c00 = *(const float4*)(bPtr0 + o);      c01 = *(const float4*)(bPtr0 + o + 4);
      c02 = *(const float4*)(bPtr0 + o + 32); c03 = *(const float4*)(bPtr0 + o + 36);
      if (isDepth) {
        d00 = *(const float4*)(bPtr1 + o);      d01 = *(const float4*)(bPtr1 + o + 4);
        d02 = *(const float4*)(bPtr1 + o + 32); d03 = *(const float4*)(bPtr1 + o + 36);
      }
    }
    #pragma unroll
    for (int ks = 0; ks < 2; ++ks) {
      bf16x8 bq0 = *(const bf16x8*)(&sB[16 * w + ln][ks * 32 + q * 8]);
      if (!isDepth) {
        #pragma unroll
        for (int i = 0; i < 2; ++i) {
          bf16x8 aq = *(const bf16x8*)(&sA[16 * i + ln][ks * 32 + q * 8]);
          acc[0][i] = __builtin_amdgcn_mfma_f32_16x16x32_bf16(aq, bq0, acc[0][i], 0, 0, 0);
        }
      } else {
        bf16x8 bq1 = *(const bf16x8*)(&sB[64 + 16 * w + ln][ks * 32 + q * 8]);
        #pragma unroll
        for (int i = 0; i < 2; ++i) {
          bf16x8 aq = *(const bf16x8*)(&sA[16 * i + ln][ks * 32 + q * 8]);
          acc[0][i] = __builtin_amdgcn_mfma_f32_16x16x32_bf16(aq, bq0, acc[0][i], 0, 0, 0);
          acc[1][i] = __builtin_amdgcn_mfma_f32_16x16x32_bf16(aq, bq1, acc[1][i], 0, 0, 0);
        }
      }
    }
    __syncthreads();
  }

  // Epilogue. C/D layout: col = lane&15, row = 16i + 4q + r.
  if (!isDepth) {
    const int colG = ct * 64 + 16 * w + ln;
    #pragma unroll
    for (int i = 0; i < 2; ++i)
      #pragma unroll
      for (int r = 0; r < 4; ++r) {
        unsigned short hb = f2bf(acc[0][i][r]);
        P[(size_t)(m0 + 16 * i + 4 * q + r) * NR + colG] = hb;
        float v = bf2f(hb);       // norm from the SAME rounded value in P
        float s = v * v;
        s += __shfl_xor(s, 1);
        s += __shfl_xor(s, 2);
        s += __shfl_xor(s, 4);
        s += __shfl_xor(s, 8);
        if (ln == 0) sRed[w][16 * i + 4 * q + r] = s;
      }
    __syncthreads();
    if (tid < 32) {
      float* np = (ct == 0) ? nP0 : nP1;
      np[m0 + tid] = sRed[0][tid] + sRed[1][tid] + sRed[2][tid] + sRed[3][tid];
    }
  } else {
    #pragma unroll
    for (int i = 0; i < 2; ++i)
      #pragma unroll
      for (int r = 0; r < 4; ++r) {
        float s = acc[0][i][r] * acc[0][i][r] + acc[1][i][r] * acc[1][i][r];
        s += __shfl_xor(s, 1);
        s += __shfl_xor(s, 2);
        s += __shfl_xor(s, 4);
        s += __shfl_xor(s, 8);
        if (ln == 0) sRed[w][16 * i + 4 * q + r] = s;
      }
    __syncthreads();
    if (tid < 32)
      depths[m0 + tid] = sRed[0][tid] + sRed[1][tid] + sRed[2][tid] + sRed[3][tid];
  }
}

// ---------------------------------------------------------------------------
// Kernel 2: out[b,i,j] = n[i] + n[j] - 2*(Pb Pb^T)[i,j].  LDS-FREE Gram:
// MFMA fragments are loaded straight from global P (16 B/lane; a wave's 64
// lanes cover whole 64 B lines: rows 16 x (q=0..3)*16B = full 64 B spans).
// No staging, no barriers except one for the 128-float norm tile.
// ---------------------------------------------------------------------------
__global__ __launch_bounds__(256) void dist_kernel(
    const unsigned short* __restrict__ P,
    const float* __restrict__ nP0,
    const float* __restrict__ nP1,
    float* __restrict__ out)
{
  __shared__ float nIs[64], nJs[64];

  const int tid = threadIdx.x;
  const int b  = blockIdx.z;
  const int i0 = blockIdx.y * 64;
  const int j0 = blockIdx.x * 64;
  const unsigned short* Pb = P + (size_t)b * NS * NR;
  const int mB = b * NS;                  // norms are indexed by global row

  if (tid < 64) {
    nIs[tid] = nP0[mB + i0 + tid] + nP1[mB + i0 + tid];
  } else if (tid < 128) {
    const int t = tid - 64;
    nJs[t] = nP0[mB + j0 + t] + nP1[mB + j0 + t];
  }

  const int lane = tid & 63;
  const int w    = tid >> 6;
  const int ln   = lane & 15;
  const int q    = lane >> 4;

  // preload all fragments for max MLP (20 b128 loads in flight)
  bf16x8 aq[4][4], bq[4];
  #pragma unroll
  for (int ks = 0; ks < 4; ++ks) {
    bq[ks] = *(const bf16x8*)(Pb + (size_t)(j0 + 16 * w + ln) * NR + ks * 32 + q * 8);
    #pragma unroll
    for (int i = 0; i < 4; ++i)
      aq[i][ks] = *(const bf16x8*)(Pb + (size_t)(i0 + 16 * i + ln) * NR + ks * 32 + q * 8);
  }
  __syncthreads();   // norm tile ready

  f32x4 acc[4] = {};
  #pragma unroll
  for (int ks = 0; ks < 4; ++ks)
    #pragma unroll
    for (int i = 0; i < 4; ++i)
      acc[i] = __builtin_amdgcn_mfma_f32_16x16x32_bf16(aq[i][ks], bq[ks], acc[i], 0, 0, 0);

  const int col = j0 + 16 * w + ln;
  const float nj = nJs[16 * w + ln];
  float* ob = out + (size_t)b * NS * NS;
  #pragma unroll
  for (int i = 0; i < 4; ++i)
    #pragma unroll
    for (int r = 0; r < 4; ++r) {
      const int rloc = 16 * i + 4 * q + r;
      ob[(size_t)(i0 + rloc) * NS + col] = nIs[rloc] + nj - 2.0f * acc[i][r];
    }
}

// ---------------------------------------------------------------------------
extern "C" void kernel_launch(void* const* d_in, const int* in_sizes, int n_in,
                              void* d_out, int out_size, void* d_ws, size_t ws_size,
                              hipStream_t stream) {
  const float* emb   = (const float*)d_in[0];
  const float* projD = (const float*)d_in[1];
  const float* projP = (const float*)d_in[2];
  float* out = (float*)d_out;

  unsigned short* P = (unsigned short*)d_ws;                  // bf16, 1 MB
  float* nP0 = (float*)((char*)d_ws + (size_t)NM * NR * 2);   // 16 KB
  float* nP1 = nP0 + NM;                                      // 16 KB
  float* depths = out + DIST_ELEMS;                           // output [4096]

  proj_kernel<<<dim3(3, NM / 32), 256, 0, stream>>>(emb, projD, projP, P, nP0, nP1, depths);
  dist_kernel<<<dim3(NS / 64, NS / 64, NB), 256, 0, stream>>>(P, nP0, nP1, out);
}

// Round 6
// 80.398 us; speedup vs baseline: 1.3858x; 1.0491x over previous
//
#include <hip/hip_runtime.h>

// Problem constants (B,S,D,R) = (8,512,768,128)
#define NB 8
#define NS 512
#define ND 768
#define NR 128
#define NM (NB * NS)                       // 4096 rows total
#define DIST_ELEMS ((size_t)NB * NS * NS)  // 2097152

typedef short bf16x8 __attribute__((ext_vector_type(8)));  // 8 bf16 (4 VGPRs)
typedef float f32x4  __attribute__((ext_vector_type(4)));  // MFMA C/D frag

// round-half-up fp32->bf16: 2 VALU ops; the SAME rounding feeds P, the norms,
// and the Gram MFMA, so d(i,i) stays ~0.
__device__ __forceinline__ unsigned short f2bf(float f) {
  return (unsigned short)((__float_as_uint(f) + 0x8000u) >> 16);
}
__device__ __forceinline__ float bf2f(unsigned short h) {
  return __uint_as_float(((unsigned int)h) << 16);
}
__device__ __forceinline__ bf16x8 pack8(float4 lo, float4 hi) {
  bf16x8 p;
  p[0] = (short)f2bf(lo.x); p[1] = (short)f2bf(lo.y);
  p[2] = (short)f2bf(lo.z); p[3] = (short)f2bf(lo.w);
  p[4] = (short)f2bf(hi.x); p[5] = (short)f2bf(hi.y);
  p[6] = (short)f2bf(hi.z); p[7] = (short)f2bf(hi.w);
  return p;
}

// ---------------------------------------------------------------------------
// Kernel 1: proj GEMM, bf16 MFMA, M-tile 32, KT=64, 4 UNIFORM col-tiles.
// grid (128, 4) -- m0-major so the 4 ct-blocks of one m-tile are 128 apart in
// linear id === same XCD (id%8): emb tile is HBM-read once, L2-hit 3x.
//   ct=0/1: P cols 0-63 / 64-127 (projD) -> write P + norm partial nP0/nP1
//   ct=2/3: projP halves            -> norm partial nD0/nD1 (depths = sum)
// LDS row stride 72 bf16 (36 dw === 4 mod 32): b128 reads at the bank floor.
// ---------------------------------------------------------------------------
constexpr int KT  = 64;
constexpr int SAS = 72;

__global__ __launch_bounds__(256) void proj_kernel(
    const float* __restrict__ emb,
    const float* __restrict__ projD,
    const float* __restrict__ projP,
    unsigned short* __restrict__ P,       // bf16 bits, 4096x128
    float* __restrict__ nP0, float* __restrict__ nP1,   // dist norm partials
    float* __restrict__ nD0, float* __restrict__ nD1)   // depth partials
{
  __shared__ unsigned short sA[32][SAS];   // 4.6 KB
  __shared__ unsigned short sB[64][SAS];   // 9.2 KB
  __shared__ float sRed[4][32];

  const int tid = threadIdx.x;
  const int m0  = blockIdx.x * 32;
  const int ct  = blockIdx.y;              // 0..3
  const bool isP = (ct < 2);
  const float* proj = (isP ? projD : projP) + (size_t)((ct & 1) * 64) * ND;

  // A staging: 32 rows x 8 octets -> thread t: row t>>3, octet t&7
  const int ar = tid >> 3, ao = tid & 7;
  const float* aPtr = emb + (size_t)(m0 + ar) * ND + ao * 8;
  // B staging: 64 rows x 8 octets -> thread t: row t>>2, octets t&3, (t&3)+4
  const int br = tid >> 2, bo = tid & 3;
  const float* bPtr = proj + (size_t)br * ND + bo * 8;

  float4 a0, a1, c00, c01, c02, c03;
  a0  = *(const float4*)(aPtr);      a1  = *(const float4*)(aPtr + 4);
  c00 = *(const float4*)(bPtr);      c01 = *(const float4*)(bPtr + 4);
  c02 = *(const float4*)(bPtr + 32); c03 = *(const float4*)(bPtr + 36);

  const int lane = tid & 63;
  const int w    = tid >> 6;
  const int ln   = lane & 15;
  const int q    = lane >> 4;

  f32x4 acc[2] = {};   // 2 row-frags x 16 cols

  for (int kt = 0; kt < ND; kt += KT) {
    *(bf16x8*)(&sA[ar][ao * 8])       = pack8(a0, a1);
    *(bf16x8*)(&sB[br][bo * 8])       = pack8(c00, c01);
    *(bf16x8*)(&sB[br][(bo + 4) * 8]) = pack8(c02, c03);
    __syncthreads();
    if (kt + KT < ND) {  // register prefetch of next K-tile
      const int o = kt + KT;
      a0  = *(const float4*)(aPtr + o);      a1  = *(const float4*)(aPtr + o + 4);
      c00 = *(const float4*)(bPtr + o);      c01 = *(const float4*)(bPtr + o + 4);
      c02 = *(const float4*)(bPtr + o + 32); c03 = *(const float4*)(bPtr + o + 36);
    }
    #pragma unroll
    for (int ks = 0; ks < 2; ++ks) {
      bf16x8 bq = *(const bf16x8*)(&sB[16 * w + ln][ks * 32 + q * 8]);
      #pragma unroll
      for (int i = 0; i < 2; ++i) {
        bf16x8 aq = *(const bf16x8*)(&sA[16 * i + ln][ks * 32 + q * 8]);
        acc[i] = __builtin_amdgcn_mfma_f32_16x16x32_bf16(aq, bq, acc[i], 0, 0, 0);
      }
    }
    __syncthreads();
  }

  // Epilogue. C/D layout: col = lane&15, row = 16i + 4q + r.
  const int colG = (ct & 1) * 64 + 16 * w + ln;
  #pragma unroll
  for (int i = 0; i < 2; ++i)
    #pragma unroll
    for (int r = 0; r < 4; ++r) {
      unsigned short hb = f2bf(acc[i][r]);
      if (isP) P[(size_t)(m0 + 16 * i + 4 * q + r) * NR + colG] = hb;
      float v = bf2f(hb);       // norm from the SAME rounded value
      float s = v * v;
      s += __shfl_xor(s, 1);
      s += __shfl_xor(s, 2);
      s += __shfl_xor(s, 4);
      s += __shfl_xor(s, 8);
      if (ln == 0) sRed[w][16 * i + 4 * q + r] = s;
    }
  __syncthreads();
  if (tid < 32) {
    float* np = (ct == 0) ? nP0 : (ct == 1) ? nP1 : (ct == 2) ? nD0 : nD1;
    np[m0 + tid] = sRed[0][tid] + sRed[1][tid] + sRed[2][tid] + sRed[3][tid];
  }
}

// ---------------------------------------------------------------------------
// Kernel 2: out[b,i,j] = n[i] + n[j] - 2*(Pb Pb^T)[i,j].  LDS-free Gram:
// MFMA fragments straight from global P (16 B/lane, full 64 B line coverage).
// j0==0 blocks additionally combine depth partials -> depths output.
// ---------------------------------------------------------------------------
__global__ __launch_bounds__(256) void dist_kernel(
    const unsigned short* __restrict__ P,
    const float* __restrict__ nP0, const float* __restrict__ nP1,
    const float* __restrict__ nD0, const float* __restrict__ nD1,
    float* __restrict__ out,
    float* __restrict__ depths)
{
  __shared__ float nIs[64], nJs[64];

  const int tid = threadIdx.x;
  const int b  = blockIdx.z;
  const int i0 = blockIdx.y * 64;
  const int j0 = blockIdx.x * 64;
  const unsigned short* Pb = P + (size_t)b * NS * NR;
  const int mB = b * NS;                  // norms indexed by global row

  if (tid < 64) {
    nIs[tid] = nP0[mB + i0 + tid] + nP1[mB + i0 + tid];
  } else if (tid < 128) {
    const int t = tid - 64;
    nJs[t] = nP0[mB + j0 + t] + nP1[mB + j0 + t];
  } else if (blockIdx.x == 0 && tid < 192) {
    const int t = tid - 128;              // depths combine (64 blocks cover all)
    depths[mB + i0 + t] = nD0[mB + i0 + t] + nD1[mB + i0 + t];
  }

  const int lane = tid & 63;
  const int w    = tid >> 6;
  const int ln   = lane & 15;
  const int q    = lane >> 4;

  // preload all fragments for max MLP (20 b128 loads in flight)
  bf16x8 aq[4][4], bq[4];
  #pragma unroll
  for (int ks = 0; ks < 4; ++ks) {
    bq[ks] = *(const bf16x8*)(Pb + (size_t)(j0 + 16 * w + ln) * NR + ks * 32 + q * 8);
    #pragma unroll
    for (int i = 0; i < 4; ++i)
      aq[i][ks] = *(const bf16x8*)(Pb + (size_t)(i0 + 16 * i + ln) * NR + ks * 32 + q * 8);
  }
  __syncthreads();   // norm tile ready

  f32x4 acc[4] = {};
  #pragma unroll
  for (int ks = 0; ks < 4; ++ks)
    #pragma unroll
    for (int i = 0; i < 4; ++i)
      acc[i] = __builtin_amdgcn_mfma_f32_16x16x32_bf16(aq[i][ks], bq[ks], acc[i], 0, 0, 0);

  const int col = j0 + 16 * w + ln;
  const float nj = nJs[16 * w + ln];
  float* ob = out + (size_t)b * NS * NS;
  #pragma unroll
  for (int i = 0; i < 4; ++i)
    #pragma unroll
    for (int r = 0; r < 4; ++r) {
      const int rloc = 16 * i + 4 * q + r;
      ob[(size_t)(i0 + rloc) * NS + col] = nIs[rloc] + nj - 2.0f * acc[i][r];
    }
}

// ---------------------------------------------------------------------------
extern "C" void kernel_launch(void* const* d_in, const int* in_sizes, int n_in,
                              void* d_out, int out_size, void* d_ws, size_t ws_size,
                              hipStream_t stream) {
  const float* emb   = (const float*)d_in[0];
  const float* projD = (const float*)d_in[1];
  const float* projP = (const float*)d_in[2];
  float* out = (float*)d_out;

  unsigned short* P = (unsigned short*)d_ws;                  // bf16, 1 MB
  float* nP0 = (float*)((char*)d_ws + (size_t)NM * NR * 2);
  float* nP1 = nP0 + NM;
  float* nD0 = nP1 + NM;
  float* nD1 = nD0 + NM;
  float* depths = out + DIST_ELEMS;                           // output [4096]

  proj_kernel<<<dim3(NM / 32, 4), 256, 0, stream>>>(emb, projD, projP, P, nP0, nP1, nD0, nD1);
  dist_kernel<<<dim3(NS / 64, NS / 64, NB), 256, 0, stream>>>(P, nP0, nP1, nD0, nD1, out, depths);
}

// Round 7
// 78.612 us; speedup vs baseline: 1.4173x; 1.0227x over previous
//
#include <hip/hip_runtime.h>

// Problem constants (B,S,D,R) = (8,512,768,128)
#define NB 8
#define NS 512
#define ND 768
#define NR 128
#define NM (NB * NS)                       // 4096 rows total
#define DIST_ELEMS ((size_t)NB * NS * NS)  // 2097152

typedef short bf16x8 __attribute__((ext_vector_type(8)));  // 8 bf16 (4 VGPRs)
typedef float f32x4  __attribute__((ext_vector_type(4)));  // MFMA C/D frag

// round-half-up fp32->bf16: 2 VALU ops; the SAME rounding feeds P, the norms,
// and the Gram MFMA, so d(i,i) stays ~0.
__device__ __forceinline__ unsigned short f2bf(float f) {
  return (unsigned short)((__float_as_uint(f) + 0x8000u) >> 16);
}
__device__ __forceinline__ float bf2f(unsigned short h) {
  return __uint_as_float(((unsigned int)h) << 16);
}
__device__ __forceinline__ bf16x8 pack8(float4 lo, float4 hi) {
  bf16x8 p;
  p[0] = (short)f2bf(lo.x); p[1] = (short)f2bf(lo.y);
  p[2] = (short)f2bf(lo.z); p[3] = (short)f2bf(lo.w);
  p[4] = (short)f2bf(hi.x); p[5] = (short)f2bf(hi.y);
  p[6] = (short)f2bf(hi.z); p[7] = (short)f2bf(hi.w);
  return p;
}

// ---------------------------------------------------------------------------
// Kernel 1: proj GEMM, bf16 MFMA, M-tile 32, KT=128 (6 barrier iterations).
// grid (128, 4) -- m0-major so the 4 ct-blocks of one m-tile are 128 apart in
// linear id === same XCD (id%8): emb tile is HBM-read once, L2-hit 3x.
//   ct=0/1: P cols 0-63 / 64-127 (projD) -> write P + norm partial nP0/nP1
//   ct=2/3: projP halves                 -> norm partial nD0/nD1
// LDS row stride 136 bf16 (68 dw === 4 mod 32): b128 frag reads AND staging
// writes have uniform bytes/bank (the b128 bank floor).
// ---------------------------------------------------------------------------
constexpr int KT  = 128;
constexpr int SAS = 136;

__global__ __launch_bounds__(256) void proj_kernel(
    const float* __restrict__ emb,
    const float* __restrict__ projD,
    const float* __restrict__ projP,
    unsigned short* __restrict__ P,       // bf16 bits, 4096x128
    float* __restrict__ nP0, float* __restrict__ nP1,   // dist norm partials
    float* __restrict__ nD0, float* __restrict__ nD1)   // depth partials
{
  __shared__ unsigned short sA[32][SAS];   // 8.7 KB
  __shared__ unsigned short sB[64][SAS];   // 17.4 KB
  __shared__ float sRed[4][32];

  const int tid = threadIdx.x;
  const int m0  = blockIdx.x * 32;
  const int ct  = blockIdx.y;              // 0..3
  const bool isP = (ct < 2);
  const float* proj = (isP ? projD : projP) + (size_t)((ct & 1) * 64) * ND;

  // A staging: 32 rows x 16 octets -> thread t: row t>>3, octets t&7, (t&7)+8
  const int ar = tid >> 3, ao = tid & 7;
  const float* aPtr = emb + (size_t)(m0 + ar) * ND + ao * 8;
  // B staging: 64 rows x 16 octets -> thread t: row t>>2, octets t&3,+4,+8,+12
  const int br = tid >> 2, bo = tid & 3;
  const float* bPtr = proj + (size_t)br * ND + bo * 8;

  float4 a0, a1, a2, a3;
  float4 c0, c1, c2, c3, c4, c5, c6, c7;
  a0 = *(const float4*)(aPtr);      a1 = *(const float4*)(aPtr + 4);
  a2 = *(const float4*)(aPtr + 64); a3 = *(const float4*)(aPtr + 68);
  c0 = *(const float4*)(bPtr);      c1 = *(const float4*)(bPtr + 4);
  c2 = *(const float4*)(bPtr + 32); c3 = *(const float4*)(bPtr + 36);
  c4 = *(const float4*)(bPtr + 64); c5 = *(const float4*)(bPtr + 68);
  c6 = *(const float4*)(bPtr + 96); c7 = *(const float4*)(bPtr + 100);

  const int lane = tid & 63;
  const int w    = tid >> 6;
  const int ln   = lane & 15;
  const int q    = lane >> 4;

  f32x4 acc[2] = {};   // 2 row-frags x 16 cols

  for (int kt = 0; kt < ND; kt += KT) {
    *(bf16x8*)(&sA[ar][ao * 8])        = pack8(a0, a1);
    *(bf16x8*)(&sA[ar][(ao + 8) * 8])  = pack8(a2, a3);
    *(bf16x8*)(&sB[br][bo * 8])        = pack8(c0, c1);
    *(bf16x8*)(&sB[br][(bo + 4) * 8])  = pack8(c2, c3);
    *(bf16x8*)(&sB[br][(bo + 8) * 8])  = pack8(c4, c5);
    *(bf16x8*)(&sB[br][(bo + 12) * 8]) = pack8(c6, c7);
    __syncthreads();
    if (kt + KT < ND) {  // register prefetch of next K-tile (12 b128 in flight)
      const int o = kt + KT;
      a0 = *(const float4*)(aPtr + o);      a1 = *(const float4*)(aPtr + o + 4);
      a2 = *(const float4*)(aPtr + o + 64); a3 = *(const float4*)(aPtr + o + 68);
      c0 = *(const float4*)(bPtr + o);      c1 = *(const float4*)(bPtr + o + 4);
      c2 = *(const float4*)(bPtr + o + 32); c3 = *(const float4*)(bPtr + o + 36);
      c4 = *(const float4*)(bPtr + o + 64); c5 = *(const float4*)(bPtr + o + 68);
      c6 = *(const float4*)(bPtr + o + 96); c7 = *(const float4*)(bPtr + o + 100);
    }
    #pragma unroll
    for (int ks = 0; ks < 4; ++ks) {
      bf16x8 bq = *(const bf16x8*)(&sB[16 * w + ln][ks * 32 + q * 8]);
      #pragma unroll
      for (int i = 0; i < 2; ++i) {
        bf16x8 aq = *(const bf16x8*)(&sA[16 * i + ln][ks * 32 + q * 8]);
        acc[i] = __builtin_amdgcn_mfma_f32_16x16x32_bf16(aq, bq, acc[i], 0, 0, 0);
      }
    }
    __syncthreads();
  }

  // Epilogue. C/D layout: col = lane&15, row = 16i + 4q + r.
  const int colG = (ct & 1) * 64 + 16 * w + ln;
  #pragma unroll
  for (int i = 0; i < 2; ++i)
    #pragma unroll
    for (int r = 0; r < 4; ++r) {
      unsigned short hb = f2bf(acc[i][r]);
      if (isP) P[(size_t)(m0 + 16 * i + 4 * q + r) * NR + colG] = hb;
      float v = bf2f(hb);       // norm from the SAME rounded value
      float s = v * v;
      s += __shfl_xor(s, 1);
      s += __shfl_xor(s, 2);
      s += __shfl_xor(s, 4);
      s += __shfl_xor(s, 8);
      if (ln == 0) sRed[w][16 * i + 4 * q + r] = s;
    }
  __syncthreads();
  if (tid < 32) {
    float* np = (ct == 0) ? nP0 : (ct == 1) ? nP1 : (ct == 2) ? nD0 : nD1;
    np[m0 + tid] = sRed[0][tid] + sRed[1][tid] + sRed[2][tid] + sRed[3][tid];
  }
}

// ---------------------------------------------------------------------------
// Kernel 2: out[b,i,j] = n[i] + n[j] - 2*(Pb Pb^T)[i,j].  LDS-free Gram:
// MFMA fragments straight from global P (16 B/lane, full 64 B line coverage).
// j0==0 blocks additionally combine depth partials -> depths output.
// ---------------------------------------------------------------------------
__global__ __launch_bounds__(256) void dist_kernel(
    const unsigned short* __restrict__ P,
    const float* __restrict__ nP0, const float* __restrict__ nP1,
    const float* __restrict__ nD0, const float* __restrict__ nD1,
    float* __restrict__ out,
    float* __restrict__ depths)
{
  __shared__ float nIs[64], nJs[64];

  const int tid = threadIdx.x;
  const int b  = blockIdx.z;
  const int i0 = blockIdx.y * 64;
  const int j0 = blockIdx.x * 64;
  const unsigned short* Pb = P + (size_t)b * NS * NR;
  const int mB = b * NS;                  // norms indexed by global row

  if (tid < 64) {
    nIs[tid] = nP0[mB + i0 + tid] + nP1[mB + i0 + tid];
  } else if (tid < 128) {
    const int t = tid - 64;
    nJs[t] = nP0[mB + j0 + t] + nP1[mB + j0 + t];
  } else if (blockIdx.x == 0 && tid < 192) {
    const int t = tid - 128;              // depths combine (64 blocks cover all)
    depths[mB + i0 + t] = nD0[mB + i0 + t] + nD1[mB + i0 + t];
  }

  const int lane = tid & 63;
  const int w    = tid >> 6;
  const int ln   = lane & 15;
  const int q    = lane >> 4;

  // preload all fragments for max MLP (20 b128 loads in flight)
  bf16x8 aq[4][4], bq[4];
  #pragma unroll
  for (int ks = 0; ks < 4; ++ks) {
    bq[ks] = *(const bf16x8*)(Pb + (size_t)(j0 + 16 * w + ln) * NR + ks * 32 + q * 8);
    #pragma unroll
    for (int i = 0; i < 4; ++i)
      aq[i][ks] = *(const bf16x8*)(Pb + (size_t)(i0 + 16 * i + ln) * NR + ks * 32 + q * 8);
  }
  __syncthreads();   // norm tile ready

  f32x4 acc[4] = {};
  #pragma unroll
  for (int ks = 0; ks < 4; ++ks)
    #pragma unroll
    for (int i = 0; i < 4; ++i)
      acc[i] = __builtin_amdgcn_mfma_f32_16x16x32_bf16(aq[i][ks], bq[ks], acc[i], 0, 0, 0);

  const int col = j0 + 16 * w + ln;
  const float nj = nJs[16 * w + ln];
  float* ob = out + (size_t)b * NS * NS;
  #pragma unroll
  for (int i = 0; i < 4; ++i)
    #pragma unroll
    for (int r = 0; r < 4; ++r) {
      const int rloc = 16 * i + 4 * q + r;
      ob[(size_t)(i0 + rloc) * NS + col] = nIs[rloc] + nj - 2.0f * acc[i][r];
    }
}

// ---------------------------------------------------------------------------
extern "C" void kernel_launch(void* const* d_in, const int* in_sizes, int n_in,
                              void* d_out, int out_size, void* d_ws, size_t ws_size,
                              hipStream_t stream) {
  const float* emb   = (const float*)d_in[0];
  const float* projD = (const float*)d_in[1];
  const float* projP = (const float*)d_in[2];
  float* out = (float*)d_out;

  unsigned short* P = (unsigned short*)d_ws;                  // bf16, 1 MB
  float* nP0 = (float*)((char*)d_ws + (size_t)NM * NR * 2);
  float* nP1 = nP0 + NM;
  float* nD0 = nP1 + NM;
  float* nD1 = nD0 + NM;
  float* depths = out + DIST_ELEMS;                           // output [4096]

  proj_kernel<<<dim3(NM / 32, 4), 256, 0, stream>>>(emb, projD, projP, P, nP0, nP1, nD0, nD1);
  dist_kernel<<<dim3(NS / 64, NS / 64, NB), 256, 0, stream>>>(P, nP0, nP1, nD0, nD1, out, depths);
}